// Round 13
// baseline (9202.839 us; speedup 1.0000x reference)
//
#include <hip/hip_runtime.h>

#define SS 4096
#define TT 2048

// clang native vector types: usable directly in asm "v" constraints
typedef float v4f __attribute__((ext_vector_type(4)));
typedef float v2f __attribute__((ext_vector_type(2)));
typedef unsigned u4 __attribute__((ext_vector_type(4)));

// ---------- LLC-coherent (agent) memory ops, hand-rolled ----------
// sc0 sc1 => bypass non-coherent per-XCD L2, serve at Infinity Cache.

// one dwordx4: thread's full packed-q poll slice (4 words = 8 bf16 cols).
// vmcnt(0) also completes any of OUR writes still in flight (merged drain).
__device__ __forceinline__ void llc_load1(const u4* p, u4& a) {
  asm volatile(
      "global_load_dwordx4 %0, %1, off sc0 sc1\n\t"
      "s_waitcnt vmcnt(0)"
      : "=&v"(a) : "v"(p) : "memory");
}

// prologue-only: store + drain
__device__ __forceinline__ void llc_storew_drain(unsigned* p, unsigned v) {
  asm volatile("global_store_dword %0, %1, off sc0 sc1\n\t"
               "s_waitcnt vmcnt(0)"
               :: "v"(p), "v"(v) : "memory");
}

// main-loop store: NO drain here; the next poll's vmcnt(0) (~15 instrs
// later) completes it. Promptness preserved (r8's storm was traced to
// emit-prefetch distance via r10, not to drain placement).
#define LLC_STOREW_NODRAIN(p, v) \
  asm volatile("global_store_dword %0, %1, off sc0 sc1" \
               :: "v"(p), "v"(v) : "memory")

// lgkm-only barrier: LDS visibility without the compiler's vmem drain
// (keeps the emit load + q store in flight across the barrier).
__device__ __forceinline__ void bar_lgkm() {
  asm volatile("s_waitcnt lgkmcnt(0)" ::: "memory");
  __builtin_amdgcn_s_barrier();
}

// straggle side-channel: LDS bank conflict burst (lanes -> bank 0).
// SQ_LDS_BANK_CONFLICT increments per retry pass => retry counter.
__device__ __forceinline__ void straggle_tick(int lane) {
  float dummy;
  asm volatile("ds_read_b32 %0, %1\n\t"
               "s_waitcnt lgkmcnt(0)"
               : "=v"(dummy) : "v"(lane << 7) : "memory");
  asm volatile("" :: "v"(dummy));
}

// ---------- helpers ----------

__device__ __forceinline__ unsigned short f2bf_rn(float f) {
  unsigned int u = __float_as_uint(f);
  u += 0x7FFFu + ((u >> 16) & 1u);   // RNE; sign preserved
  return (unsigned short)(u >> 16);
}

__device__ __forceinline__ float blo(unsigned w) { return __uint_as_float(w << 16); }
__device__ __forceinline__ float bhi(unsigned w) { return __uint_as_float(w & 0xFFFF0000u); }

// ---------- persistent forward recursion: TRANSPOSED GEMV, PACKED-BF16 q ----------
// 256 blocks x 512 threads (8 waves), 1 block/CU, waves_per_eu(2,2).
// r12 structure (verified) with the detect path restructured:
//  (1) EMIT AFTER DETECT: emit[t] is issued only after the poll passes;
//      its ~900cyc HBM latency hides under GEMV+butterfly+combine
//      (~1200cyc). Detect = q-visibility only (was max(q, emit-HBM)).
//      Barrier1 is lgkm-only so no vmem drain catches the emit load.
//  (2) MERGED DRAIN: q store issued without drain; the NEXT poll's
//      vmcnt(0) completes it. Saves a full serial RT per step.
//  (3) OWN-WORD SPLICE: block b's 8 packed words are polled by exactly
//      threads 2b,2b+1; lane0 of each wave writes pw to qownw[8] (LDS),
//      ordered by lgkm-barrier2; those threads splice from LDS and never
//      wait on their own store's RT (also kills the same-address
//      store->load hazard the merged drain would create).
// Sign protocol unchanged: stored sign of step t is s_t=((t>>1)&1)?-1:+1
// (bf16 sign bits both halves); readiness mask 0x80008000; output scale
// folds s_t*s_{t-1} (+ odd t, - even t); 0xAA poison negative, only ever
// polled where positive expected.
#define K16(X) X(0) X(1) X(2) X(3) X(4) X(5) X(6) X(7) \
               X(8) X(9) X(10) X(11) X(12) X(13) X(14) X(15)

__global__ void __launch_bounds__(512, 1) __attribute__((amdgpu_waves_per_eu(2, 2)))
hmm_fwd(const float* __restrict__ lt, const float* __restrict__ lm0,
        const float* __restrict__ emit, unsigned* qp, float* out) {
  __shared__ float part[2][8 * 17];        // padded partials, double-buffered
  __shared__ unsigned qownw[8];            // this block's 8 pw words (step t)
  __shared__ float wsum[8];
  const int b     = blockIdx.x;
  const int tid   = threadIdx.x;
  const int wave  = tid >> 6;
  const int lane  = tid & 63;
  const int row0  = (b << 4) + (wave << 1);   // this wave's 2 global rows
  const int word0 = (b << 3) + wave;          // this wave's packed q word
  const bool own  = (tid >> 1) == b;          // thread polls only own-block words

  // ---- "step 0": publish own packed q0 word FIRST ----
  {
    v2f m0v = *(const v2f*)(lm0 + row0);
    v2f e0v = *(const v2f*)(emit + row0);
    unsigned pw = (unsigned)f2bf_rn(__expf(m0v.x + e0v.x))
                | ((unsigned)f2bf_rn(__expf(m0v.y + e0v.y)) << 16);
    if (lane == 0) {
      qownw[wave] = pw;                      // seed the splice buffer
      llc_storew_drain(qp + word0, pw);      // positive = s_0
    }
  }

  // 32 named f32 E registers: eA_r = exp(lt[16b+r][8*tid .. +4]),
  //                           eB_r = exp(lt[16b+r][8*tid+4 .. +8])
#define DECL_E(r) v4f eA_##r, eB_##r;
  K16(DECL_E)
#undef DECL_E
  {
    const float* baseE = lt + ((size_t)(b << 4)) * SS + (tid << 3);
#define INIT_E(r) { \
    v4f tA = *(const v4f*)(baseE + (size_t)(r) * SS); \
    v4f tB = *(const v4f*)(baseE + (size_t)(r) * SS + 4); \
    eA_##r = (v4f){__expf(tA.x), __expf(tA.y), __expf(tA.z), __expf(tA.w)}; \
    eB_##r = (v4f){__expf(tB.x), __expf(tB.y), __expf(tB.z), __expf(tB.w)}; }
    K16(INIT_E)
#undef INIT_E
  }
  __syncthreads();   // one-time: qownw + prologue visible block-wide

  for (int t = 1; t <= TT; ++t) {
    // poll own packed slice: expected stored-sign of step t-1.
    // vmcnt(0) inside also completes OUR last store (merged drain).
    const unsigned em32 = (((t - 1) >> 1) & 1) ? 0x80008000u : 0u;
    const u4* qsrc = (const u4*)(qp + ((t - 1) & 1) * 2048) + tid;
    u4 w;
    llc_load1(qsrc, w);
    if (own) {   // splice: bits identical to what LLC will eventually show
      const int o4 = (tid & 1) << 2;
      w.x = qownw[o4 + 0];  w.y = qownw[o4 + 1];
      w.z = qownw[o4 + 2];  w.w = qownw[o4 + 3];
    }
    if ((((w.x ^ em32) | (w.y ^ em32) | (w.z ^ em32) | (w.w ^ em32))
         & 0x80008000u)) {
      for (;;) {   // own threads never enter (spliced signs always pass)
        straggle_tick(lane);   // side-channel: count this pass
        llc_load1(qsrc, w);
        if (!(((w.x ^ em32) | (w.y ^ em32) | (w.z ^ em32) | (w.w ^ em32))
              & 0x80008000u)) break;
      }
    }

    // emit[t]: issued AFTER detect; latency hides under the compute below
    v2f em;
    if (lane == 0) em = *(const v2f*)(emit + (size_t)t * SS + row0);

    // unpack RAW (sign s_{t-1} kept; folded into output scale)
    v4f va = {blo(w.x), bhi(w.x), blo(w.y), bhi(w.y)};
    v4f vb = {blo(w.z), bhi(w.z), blo(w.w), bhi(w.w)};

    // transposed GEMV straight from registers: 16 row-partials over own 8 cols
#define DECL_H(r) float h##r;
    K16(DECL_H)
#undef DECL_H
#define GEMV_R(r) { \
    v4f p = eA_##r * va + eB_##r * vb; \
    h##r = (p.x + p.y) + (p.z + p.w); }
    K16(GEMV_R)
#undef GEMV_R

    // reduce-scatter butterfly: after masks {32,16,8,4}, lane 4r holds row r
    const bool b5 = (lane & 32) != 0;
    const bool b4 = (lane & 16) != 0;
    const bool b3 = (lane & 8) != 0;
    const bool b2 = (lane & 4) != 0;
    float n0, n1, n2, n3, n4, n5, n6, n7;
#define RS32(i, A, B) { \
    float kk = b5 ? (B) : (A); \
    float ss = b5 ? (A) : (B); \
    n##i = kk + __shfl_xor(ss, 32); }
    RS32(0, h0, h8)  RS32(1, h1, h9)  RS32(2, h2, h10) RS32(3, h3, h11)
    RS32(4, h4, h12) RS32(5, h5, h13) RS32(6, h6, h14) RS32(7, h7, h15)
#undef RS32
    float mm0, mm1, mm2, mm3;
#define RS16(i, A, B) { \
    float kk = b4 ? (B) : (A); \
    float ss = b4 ? (A) : (B); \
    mm##i = kk + __shfl_xor(ss, 16); }
    RS16(0, n0, n4) RS16(1, n1, n5) RS16(2, n2, n6) RS16(3, n3, n7)
#undef RS16
    float pp0, pp1;
#define RS8(i, A, B) { \
    float kk = b3 ? (B) : (A); \
    float ss = b3 ? (A) : (B); \
    pp##i = kk + __shfl_xor(ss, 8); }
    RS8(0, mm0, mm2) RS8(1, mm1, mm3)
#undef RS8
    float s = (b2 ? pp1 : pp0) + __shfl_xor(b2 ? pp0 : pp1, 4);
    s += __shfl_xor(s, 2);
    s += __shfl_xor(s, 1);

    // 16 writer lanes (lane = 4r) publish wave-partial for local row r
    if (!(lane & 3)) part[t & 1][wave * 17 + (lane >> 2)] = s;
    bar_lgkm();   // barrier1 (lgkm-only: emit + store stay in flight)

    // wave w combines 8 wave-partials for its rows 2w, 2w+1
    const float* pb = part[t & 1];
    float x = pb[(lane & 7) * 17 + (wave << 1) + ((lane >> 3) & 1)];
    x += __shfl_xor(x, 1);
    x += __shfl_xor(x, 2);
    x += __shfl_xor(x, 4);          // lanes 0-7: S(2w); lanes 8-15: S(2w+1)
    float y = __shfl_xor(x, 8);     // lane 0 receives S(2w+1)

    if (lane == 0) {
      float scale = ((t & 255) == 0) ? 0x1p-46f : 1.0f;  // exact pow2 renorm
      if (!(t & 1)) scale = -scale;                       // s_t * s_{t-1}
      float rx = x * (__expf(em.x) * scale);
      float ry = y * (__expf(em.y) * scale);
      unsigned pw = (unsigned)f2bf_rn(rx) | ((unsigned)f2bf_rn(ry) << 16);
      qownw[wave] = pw;                                  // splice source
      LLC_STOREW_NODRAIN(qp + (t & 1) * 2048 + word0, pw);
    }
    bar_lgkm();   // barrier2: qownw visible before any wave's next poll
  }

  // complete the final store before reading q_T back
  asm volatile("s_waitcnt vmcnt(0)" ::: "memory");

  // final reduction: q_T (t=2048) in buffer 0, stored sign positive
  if (b == 0) {
    const u4* qf = (const u4*)qp + tid;   // 512 threads x 4 words = 2048
    u4 w;
    for (;;) {
      llc_load1(qf, w);
      if (!((w.x | w.y | w.z | w.w) & 0x80008000u)) break;
    }
    float s = blo(w.x) + bhi(w.x) + blo(w.y) + bhi(w.y)
            + blo(w.z) + bhi(w.z) + blo(w.w) + bhi(w.w);
#pragma unroll
    for (int m = 32; m > 0; m >>= 1) s += __shfl_xor(s, m);
    if (lane == 0) wsum[wave] = s;
    __syncthreads();
    if (tid == 0) {
      float tot = 0.f;
#pragma unroll
      for (int i = 0; i < 8; ++i) tot += wsum[i];
      out[0] = logf(tot) + 368.0f * 0.693147180559945f;   // 8 rescales * 46 * ln2
    }
  }
}

// ---------- launch ----------
extern "C" void kernel_launch(void* const* d_in, const int* in_sizes, int n_in,
                              void* d_out, int out_size, void* d_ws, size_t ws_size,
                              hipStream_t stream) {
  const float* log_M0    = (const float*)d_in[0];
  const float* log_trans = (const float*)d_in[1];
  const float* log_emit  = (const float*)d_in[2];
  // d_in[3] = T (fixed 2048, unused)

  unsigned* qp = (unsigned*)d_ws;   // 2 x 8 KiB packed bf16 (0xAA poison = negative)
  float* out   = (float*)d_out;

  hipLaunchKernelGGL(hmm_fwd, dim3(256), dim3(512), 0, stream,
                     log_trans, log_M0, log_emit, qp, out);
}

// Round 14
// 8740.958 us; speedup vs baseline: 1.0528x; 1.0528x over previous
//
#include <hip/hip_runtime.h>

#define SS 4096
#define TT 2048

// clang native vector types: usable directly in asm "v" constraints
typedef float v4f __attribute__((ext_vector_type(4)));
typedef float v2f __attribute__((ext_vector_type(2)));

// ---------- LLC-coherent (agent) memory ops, hand-rolled ----------
// sc0 sc1 => bypass non-coherent per-XCD L2, serve at Infinity Cache.

// two v4f, 8KB apart (thread's two poll slices). The vmcnt(0) here ALSO
// completes our previous step's store (merged drain) + the emit load.
__device__ __forceinline__ void llc_load2(const v4f* p, v4f& a, v4f& b) {
  asm volatile(
      "global_load_dwordx4 %0, %2, off sc0 sc1\n\t"
      "global_load_dwordx4 %1, %3, off sc0 sc1\n\t"
      "s_waitcnt vmcnt(0)"
      : "=&v"(a), "=&v"(b)
      : "v"(p), "v"(p + 512)
      : "memory");
}

__device__ __forceinline__ void llc_load4x4(const v4f* p,
                                            v4f& a, v4f& b, v4f& c, v4f& d) {
  asm volatile(
      "global_load_dwordx4 %0, %4, off sc0 sc1\n\t"
      "global_load_dwordx4 %1, %5, off sc0 sc1\n\t"
      "global_load_dwordx4 %2, %6, off sc0 sc1\n\t"
      "global_load_dwordx4 %3, %7, off sc0 sc1\n\t"
      "s_waitcnt vmcnt(0)"
      : "=&v"(a), "=&v"(b), "=&v"(c), "=&v"(d)
      : "v"(p), "v"(p + 256), "v"(p + 512), "v"(p + 768)
      : "memory");
}

// sentinel poll: word 0 of each 8B chunk (4B x 4).
__device__ __forceinline__ void llc_sent4(const float* p0, const float* p1,
                                          const float* p2, const float* p3,
                                          float& a, float& b, float& c, float& d) {
  asm volatile(
      "global_load_dword %0, %4, off sc0 sc1\n\t"
      "global_load_dword %1, %5, off sc0 sc1\n\t"
      "global_load_dword %2, %6, off sc0 sc1\n\t"
      "global_load_dword %3, %7, off sc0 sc1\n\t"
      "s_waitcnt vmcnt(0)"
      : "=&v"(a), "=&v"(b), "=&v"(c), "=&v"(d)
      : "v"(p0), "v"(p1), "v"(p2), "v"(p3)
      : "memory");
}

// prologue-only: store + drain
__device__ __forceinline__ void llc_store2_drain(float* p, v2f v) {
  asm volatile("global_store_dwordx2 %0, %1, off sc0 sc1\n\t"
               "s_waitcnt vmcnt(0)"
               :: "v"(p), "v"(v) : "memory");
}

// main-loop store: NO drain; the NEXT poll's vmcnt(0) (~20 instrs later)
// completes it. Store ISSUE time unchanged vs r11 — only the producer's
// private stall is removed. (r8/r13 regressions are attributed to the
// missing emit-grace, which THIS kernel keeps — the single variable here.)
#define LLC_STORE2_NODRAIN(p, v) \
  asm volatile("global_store_dwordx2 %0, %1, off sc0 sc1" \
               :: "v"(p), "v"(v) : "memory")

// straggle side-channel: LDS bank conflict burst. NOTE (r13 lesson):
// conflict count scales with the active exec mask, so this UNDER-COUNTS
// when few lanes retry — read it as a lower bound.
__device__ __forceinline__ void straggle_tick(int lane) {
  float dummy;
  asm volatile("ds_read_b32 %0, %1\n\t"
               "s_waitcnt lgkmcnt(0)"
               : "=v"(dummy) : "v"(lane << 7) : "memory");
  asm volatile("" :: "v"(dummy));
}

// OR of (sign-adjusted) words: ready iff top bit of result is 0
__device__ __forceinline__ unsigned orsgn(v4f v, unsigned e) {
  return (__float_as_uint(v.x) ^ e) | (__float_as_uint(v.y) ^ e)
       | (__float_as_uint(v.z) ^ e) | (__float_as_uint(v.w) ^ e);
}

// ---------- persistent forward recursion: TRANSPOSED GEMV (r11 + merged drain) ----------
// 256 blocks x 512 threads (8 waves), 1 block/CU, waves_per_eu(2,2).
// EXACT r11 structure (verified 4588us): thread tid polls q cols [4t,+4)
// and [4t+2048,+4); transposed GEMV from 32 named f32 E regs; reduce-
// scatter butterfly; 16 writer lanes -> padded LDS partials; ONE barrier;
// wave combines; lane0 stores 8B. Emit load INSIDE the poll drain (grace).
// SINGLE CHANGE vs r11: the q store's vmcnt(0) is merged into the next
// poll's vmcnt(0). Store data pinned via loop-carried r_keep, released
// after that drain; final vmcnt(0) after the loop.
// Sign protocol: stored sign of step t is s_t = ((t>>1)&1)?-1:+1; output
// scale folds s_t*s_{t-1} (+ odd t, - even t); 0xAA poison negative.
// Own-word self-read may race our own in-flight store -> at most one
// cheap retry for threads 2b,2b+1 (retry refetches until sign flips).
#define K16(X) X(0) X(1) X(2) X(3) X(4) X(5) X(6) X(7) \
               X(8) X(9) X(10) X(11) X(12) X(13) X(14) X(15)

__global__ void __launch_bounds__(512, 1) __attribute__((amdgpu_waves_per_eu(2, 2)))
hmm_fwd(const float* __restrict__ lt, const float* __restrict__ lm0,
        const float* __restrict__ emit, float* q, float* out) {
  __shared__ float part[2][8 * 17];        // padded partials, double-buffered
  __shared__ float wsum[8];
  const int b    = blockIdx.x;
  const int tid  = threadIdx.x;
  const int wave = tid >> 6;
  const int lane = tid & 63;
  const int row0 = (b << 4) + (wave << 1);   // this wave's 2 global rows

  // ---- "step 0": publish own q0 slice FIRST (consumers poll it at t=1) ----
  {
    v2f m0v = *(const v2f*)(lm0 + row0);
    v2f e0v = *(const v2f*)(emit + row0);
    v2f q0;
    q0.x = __expf(m0v.x + e0v.x);            // positive = stored sign s_0
    q0.y = __expf(m0v.y + e0v.y);
    if (lane == 0) llc_store2_drain(q + row0, q0);
  }

  // 32 named f32 E registers: eA_r = exp(lt[16b+r][4*tid .. +4]),
  //                           eB_r = exp(lt[16b+r][4*tid+2048 .. +4])
#define DECL_E(r) v4f eA_##r, eB_##r;
  K16(DECL_E)
#undef DECL_E
  {
    const float* baseE = lt + ((size_t)(b << 4)) * SS + (tid << 2);
#define INIT_E(r) { \
    v4f tA = *(const v4f*)(baseE + (size_t)(r) * SS); \
    v4f tB = *(const v4f*)(baseE + (size_t)(r) * SS + 2048); \
    eA_##r = (v4f){__expf(tA.x), __expf(tA.y), __expf(tA.z), __expf(tA.w)}; \
    eB_##r = (v4f){__expf(tB.x), __expf(tB.y), __expf(tB.z), __expf(tB.w)}; }
    K16(INIT_E)
#undef INIT_E
  }

  v2f r_keep = {0.f, 0.f};   // pins in-flight store data until next drain

  for (int t = 1; t <= TT; ++t) {
    // emit load: issued right before the poll, drained BY the poll (its
    // HBM latency doubles as the poll grace period — the r9/r11 placement)
    v2f em;
    if (lane == 0) em = *(const v2f*)(emit + (size_t)t * SS + row0);

    // poll own q slices: expected stored-sign of step t-1 (r11-identical).
    // The vmcnt(0) inside llc_load2 also completes our last store.
    const unsigned e = (unsigned)(((t - 1) >> 1) & 1) << 31;
    const v4f* qsrc4 = (const v4f*)(q + ((t - 1) & 1) * SS);
    v4f va, vb;
    llc_load2(qsrc4 + tid, va, vb);
    asm volatile("" :: "v"(r_keep));   // store drained here: release pin
    {
      unsigned o = orsgn(va, e) | orsgn(vb, e);
      if (o >> 31) {
        const float* qw = (const float*)qsrc4;
        const float* p0 = qw + (tid << 2);
        const float* p1 = p0 + 2;
        const float* p2 = p0 + 2048;
        const float* p3 = p0 + 2050;
        for (;;) {
          straggle_tick(lane);   // side-channel: count this pass (lower bound)
          float s0v, s1v, s2v, s3v;
          llc_sent4(p0, p1, p2, p3, s0v, s1v, s2v, s3v);
          unsigned so = (__float_as_uint(s0v) ^ e) | (__float_as_uint(s1v) ^ e)
                      | (__float_as_uint(s2v) ^ e) | (__float_as_uint(s3v) ^ e);
          if (!(so >> 31)) break;
        }
        llc_load2(qsrc4 + tid, va, vb);   // data now LLC-resident
      }
    }

    // transposed GEMV straight from registers: 16 row-partials over own 8 cols
#define DECL_H(r) float h##r;
    K16(DECL_H)
#undef DECL_H
#define GEMV_R(r) { \
    v4f p = eA_##r * va + eB_##r * vb; \
    h##r = (p.x + p.y) + (p.z + p.w); }
    K16(GEMV_R)
#undef GEMV_R

    // reduce-scatter butterfly: after masks {32,16,8,4}, lane 4r holds row r
    // summed over this wave's 64 lanes; masks {2,1} broadcast within quads.
    const bool b5 = (lane & 32) != 0;
    const bool b4 = (lane & 16) != 0;
    const bool b3 = (lane & 8) != 0;
    const bool b2 = (lane & 4) != 0;
    float n0, n1, n2, n3, n4, n5, n6, n7;
#define RS32(i, A, B) { \
    float kk = b5 ? (B) : (A); \
    float ss = b5 ? (A) : (B); \
    n##i = kk + __shfl_xor(ss, 32); }
    RS32(0, h0, h8)  RS32(1, h1, h9)  RS32(2, h2, h10) RS32(3, h3, h11)
    RS32(4, h4, h12) RS32(5, h5, h13) RS32(6, h6, h14) RS32(7, h7, h15)
#undef RS32
    float mm0, mm1, mm2, mm3;
#define RS16(i, A, B) { \
    float kk = b4 ? (B) : (A); \
    float ss = b4 ? (A) : (B); \
    mm##i = kk + __shfl_xor(ss, 16); }
    RS16(0, n0, n4) RS16(1, n1, n5) RS16(2, n2, n6) RS16(3, n3, n7)
#undef RS16
    float pp0, pp1;
#define RS8(i, A, B) { \
    float kk = b3 ? (B) : (A); \
    float ss = b3 ? (A) : (B); \
    pp##i = kk + __shfl_xor(ss, 8); }
    RS8(0, mm0, mm2) RS8(1, mm1, mm3)
#undef RS8
    float s = (b2 ? pp1 : pp0) + __shfl_xor(b2 ? pp0 : pp1, 4);
    s += __shfl_xor(s, 2);
    s += __shfl_xor(s, 1);

    // 16 writer lanes (lane = 4r) publish wave-partial for local row r
    if (!(lane & 3)) part[t & 1][wave * 17 + (lane >> 2)] = s;
    __syncthreads();   // single barrier per step (partials double-buffered)

    // wave w combines 8 wave-partials for its rows 2w, 2w+1
    const float* pb = part[t & 1];
    float x = pb[(lane & 7) * 17 + (wave << 1) + ((lane >> 3) & 1)];
    x += __shfl_xor(x, 1);
    x += __shfl_xor(x, 2);
    x += __shfl_xor(x, 4);          // lanes 0-7: S(2w); lanes 8-15: S(2w+1)
    float y = __shfl_xor(x, 8);     // lane 0 receives S(2w+1)

    if (lane == 0) {
      float scale = ((t & 255) == 0) ? 0x1p-46f : 1.0f;  // exact pow2 renorm
      if (!(t & 1)) scale = -scale;                       // s_t * s_{t-1}
      v2f r;
      r.x = x * (__expf(em.x) * scale);
      r.y = y * (__expf(em.y) * scale);
      LLC_STORE2_NODRAIN(q + (t & 1) * SS + row0, r);
      r_keep = r;   // pin store-data regs until the next poll's vmcnt(0)
    }
  }

  // complete the final store before reading q_T back
  asm volatile("" :: "v"(r_keep));
  asm volatile("s_waitcnt vmcnt(0)" ::: "memory");

  // final reduction: q_T (t=2048) in buffer 0, stored sign positive
  if (b == 0) {
    if (tid < 256) {
      const v4f* qf4 = (const v4f*)q;
      v4f va, vb, vc, vd;
      for (;;) {
        llc_load4x4(qf4 + tid, va, vb, vc, vd);
        unsigned o = orsgn(va, 0) | orsgn(vb, 0) | orsgn(vc, 0) | orsgn(vd, 0);
        if (!(o >> 31)) break;
      }
      float s = va.x + va.y + va.z + va.w + vb.x + vb.y + vb.z + vb.w
              + vc.x + vc.y + vc.z + vc.w + vd.x + vd.y + vd.z + vd.w;
#pragma unroll
      for (int m = 32; m > 0; m >>= 1) s += __shfl_xor(s, m);
      if (lane == 0) wsum[wave] = s;
    }
    __syncthreads();
    if (tid == 0) {
      float tot = wsum[0] + wsum[1] + wsum[2] + wsum[3];
      out[0] = logf(tot) + 368.0f * 0.693147180559945f;   // 8 rescales * 46 * ln2
    }
  }
}

// ---------- launch ----------
extern "C" void kernel_launch(void* const* d_in, const int* in_sizes, int n_in,
                              void* d_out, int out_size, void* d_ws, size_t ws_size,
                              hipStream_t stream) {
  const float* log_M0    = (const float*)d_in[0];
  const float* log_trans = (const float*)d_in[1];
  const float* log_emit  = (const float*)d_in[2];
  // d_in[3] = T (fixed 2048, unused)

  float* q   = (float*)d_ws;     // 2 x 16 KiB (poisoned 0xAA = negative)
  float* out = (float*)d_out;

  hipLaunchKernelGGL(hmm_fwd, dim3(256), dim3(512), 0, stream,
                     log_trans, log_M0, log_emit, q, out);
}